// Round 1
// baseline (293.276 us; speedup 1.0000x reference)
//
#include <hip/hip_runtime.h>

#define NN 50000
#define NE 800000
#define NC 64

// ---------------------------------------------------------------------------
// Stage 1: degree of target nodes (scatter-add of ones). Exact in f32.
// ---------------------------------------------------------------------------
__global__ void FusedGCN_deg_kernel(const int* __restrict__ tgt,
                                    float* __restrict__ deg) {
    int e = blockIdx.x * blockDim.x + threadIdx.x;
    if (e < NE) {
        unsafeAtomicAdd(&deg[tgt[e]], 1.0f);
    }
}

// ---------------------------------------------------------------------------
// Stage 2: deg_inv_sqrt in-place: deg[i] = (max(deg,1))^-0.5
// ---------------------------------------------------------------------------
__global__ void FusedGCN_dis_kernel(float* __restrict__ deg) {
    int i = blockIdx.x * blockDim.x + threadIdx.x;
    if (i < NN) {
        deg[i] = rsqrtf(fmaxf(deg[i], 1.0f));
    }
}

// ---------------------------------------------------------------------------
// Stage 3+4: gather x[src], scale by norm, scatter-add into agg (= d_out).
// One wave per edge; lane = channel. 64 lanes hit one contiguous 256B row.
// ---------------------------------------------------------------------------
__global__ __launch_bounds__(256) void FusedGCN_scatter_kernel(
        const float* __restrict__ x,
        const int* __restrict__ src,
        const int* __restrict__ tgt,
        const float* __restrict__ dis,
        float* __restrict__ agg) {
    int e = blockIdx.x * 4 + (threadIdx.x >> 6);
    int lane = threadIdx.x & 63;
    if (e < NE) {
        int s = src[e];
        int t = tgt[e];
        float norm = dis[s] * dis[t];
        float v = x[s * NC + lane] * norm;
        unsafeAtomicAdd(&agg[t * NC + lane], v);
    }
}

// ---------------------------------------------------------------------------
// Stage 5+6: out = relu(agg @ W^T + b), in-place on d_out.
// One wave per row. Row is fully loaded into a register before the wave
// writes it back (no cross-row dependence -> in-place is safe).
// W staged transposed in padded LDS: Wt[k][c] = W[c*64+k]; [64][65] pad
// makes both the staging stores and the per-k reads bank-conflict-free.
// ---------------------------------------------------------------------------
__global__ __launch_bounds__(256) void FusedGCN_linear_kernel(
        float* __restrict__ out,
        const float* __restrict__ W,
        const float* __restrict__ bias) {
    __shared__ float Wt[64][65];
    int tid = threadIdx.x;
#pragma unroll
    for (int i = tid; i < 64 * 64; i += 256) {
        Wt[i & 63][i >> 6] = W[i];
    }
    __syncthreads();

    int lane = tid & 63;
    int row = blockIdx.x * 4 + (tid >> 6);
    if (row < NN) {
        float a = out[row * NC + lane];   // lane c holds agg[row, c]
        float acc = bias[lane];
#pragma unroll
        for (int k = 0; k < 64; ++k) {
            // broadcast agg[row, k] from lane k; Wt[k][lane] = W[lane, k]
            acc = fmaf(__shfl(a, k), Wt[k][lane], acc);
        }
        out[row * NC + lane] = fmaxf(acc, 0.0f);
    }
}

// ---------------------------------------------------------------------------
extern "C" void kernel_launch(void* const* d_in, const int* in_sizes, int n_in,
                              void* d_out, int out_size, void* d_ws, size_t ws_size,
                              hipStream_t stream) {
    const float* x   = (const float*)d_in[0];
    const int*   ei  = (const int*)d_in[1];   // edge_index [2, E] int32
    const float* W   = (const float*)d_in[2];
    const float* b   = (const float*)d_in[3];
    const int*   src = ei;        // edge_index[0]
    const int*   tgt = ei + NE;   // edge_index[1]

    float* out = (float*)d_out;   // used as agg accumulator, then in-place linear
    float* deg = (float*)d_ws;    // N floats of scratch

    // Zero accumulators every call (graph replays; harness does not re-poison).
    hipMemsetAsync(deg, 0, NN * sizeof(float), stream);
    hipMemsetAsync(out, 0, (size_t)NN * NC * sizeof(float), stream);

    FusedGCN_deg_kernel<<<(NE + 255) / 256, 256, 0, stream>>>(tgt, deg);
    FusedGCN_dis_kernel<<<(NN + 255) / 256, 256, 0, stream>>>(deg);
    FusedGCN_scatter_kernel<<<(NE + 3) / 4, 256, 0, stream>>>(x, src, tgt, deg, out);
    FusedGCN_linear_kernel<<<(NN + 3) / 4, 256, 0, stream>>>(out, W, b);
}